// Round 3
// baseline (177.102 us; speedup 1.0000x reference)
//
#include <hip/hip_runtime.h>

// Problem constants (fixed by setup_inputs)
constexpr int B = 4, N = 2048, I = 256, H = 4, D = 64, E = 256; // E = H*D
constexpr float LOG2E = 1.44269504088896340736f;

typedef __bf16 bf16x8 __attribute__((ext_vector_type(8)));
typedef float f32x4 __attribute__((ext_vector_type(4)));
typedef unsigned short us8 __attribute__((ext_vector_type(8)));

__device__ __forceinline__ unsigned short f2bf(float f) {
    unsigned u = __builtin_bit_cast(unsigned, f);
    u = (u + 0x7FFFu + ((u >> 16) & 1u)) >> 16;  // RNE
    return (unsigned short)u;
}
__device__ __forceinline__ float bf2f(unsigned short s) {
    return __builtin_bit_cast(float, (unsigned)s << 16);
}

// ---------------- Kernel 1: per-head projection + H1/H2 (log2-scaled) + HpT(bf16) ----------------
// HpT[b][h][d][n] = bf16( sum_i X[b][n][i] * W[h][i][d] )
// H1[b][h][n] = LOG2E * dot(Hp, a[h,0:D]);  H2 with a[h,D:2D]
constexpr int NT = 8; // nodes per block

__global__ __launch_bounds__(256) void k_proj(const float* __restrict__ X,
                                              const float* __restrict__ W,
                                              const float* __restrict__ a,
                                              unsigned short* __restrict__ HpT,
                                              float* __restrict__ H1,
                                              float* __restrict__ H2) {
    int blk = blockIdx.x;
    int b = blk / (N / NT);
    int n0 = (blk % (N / NT)) * NT;
    int t = threadIdx.x;
    int h = t >> 6, d = t & 63;

    __shared__ float Xs[NT][I]; // 8 KB

    const float4* Xr = (const float4*)(X + ((size_t)b * N + n0) * I);
    #pragma unroll
    for (int k = 0; k < (NT * I / 4) / 256; ++k) { // 2 iters
        int v = t + 256 * k;
        ((float4*)&Xs[0][0])[v] = Xr[v];
    }
    __syncthreads();

    float acc[NT];
    #pragma unroll
    for (int nn = 0; nn < NT; ++nn) acc[nn] = 0.f;

    const float* Wp = W + (size_t)h * I * D + d;
    #pragma unroll 2
    for (int i4 = 0; i4 < I; i4 += 4) {
        float w0 = Wp[(size_t)(i4 + 0) * D];
        float w1 = Wp[(size_t)(i4 + 1) * D];
        float w2 = Wp[(size_t)(i4 + 2) * D];
        float w3 = Wp[(size_t)(i4 + 3) * D];
        #pragma unroll
        for (int nn = 0; nn < NT; ++nn) {
            float4 x = *(const float4*)&Xs[nn][i4];
            acc[nn] += x.x * w0 + x.y * w1 + x.z * w2 + x.w * w3;
        }
    }

    float a1 = a[h * (2 * D) + d];
    float a2 = a[h * (2 * D) + D + d];

    #pragma unroll
    for (int nn = 0; nn < NT; ++nn) {
        float v1 = acc[nn] * a1;
        float v2 = acc[nn] * a2;
        #pragma unroll
        for (int off = 32; off > 0; off >>= 1) {
            v1 += __shfl_down(v1, off, 64);
            v2 += __shfl_down(v2, off, 64);
        }
        if (d == 0) {
            H1[(size_t)(b * H + h) * N + (n0 + nn)] = v1 * LOG2E;
            H2[(size_t)(b * H + h) * N + (n0 + nn)] = v2 * LOG2E;
        }
    }

    // transposed bf16 store: 8 consecutive n per thread at row d
    us8 o;
    #pragma unroll
    for (int nn = 0; nn < NT; ++nn) o[nn] = f2bf(acc[nn]);
    *(us8*)&HpT[((size_t)(b * H + h) * D + d) * N + n0] = o;
}

// ---------------- Kernel 2: barrier-free per-wave head-softmax + MFMA aggregation ----------------
// One wave per (b, i-tile of 16, j-split). Lane l computes the 4-head softmax for
// its own A-fragment slots (row=l&15, k=(l>>4)*8+e) and keeps all 4 heads' weights
// in registers; wave issues 4 heads x 4 d-tiles MFMAs per 32-j step. No LDS/barriers.
constexpr int JSPL = 4;
constexpr int JRANGE = N / JSPL;    // 512
constexpr int NSTEP = JRANGE / 32;  // 16
constexpr int PART = B * H * N * D; // u16 elems per partial buffer

__global__ __launch_bounds__(64) void k_agg(const int* __restrict__ A,
                                            const float* __restrict__ H1,
                                            const float* __restrict__ H2,
                                            const unsigned short* __restrict__ HpT,
                                            unsigned short* __restrict__ part) {
    int bid = blockIdx.x;
    int js = bid & (JSPL - 1);
    int it = (bid >> 2) & 127;   // N/16 = 128
    int b  = bid >> 9;
    int i0 = it * 16;
    int jb = js * JRANGE;
    int l = threadIdx.x;
    int row = l & 15;  // A-frag row / B-frag col
    int kg = l >> 4;   // k-chunk: k = kg*8 + e

    float h1v[H];
    #pragma unroll
    for (int h = 0; h < H; ++h) h1v[h] = H1[(size_t)(b * H + h) * N + i0 + row];

    f32x4 acc[H][4] = {}; // [head][d-tile]

    const int4* Ar = (const int4*)(A + (size_t)b * N * N + (size_t)(i0 + row) * N + jb + kg * 8);
    const float* H2b = H2 + (size_t)b * H * N + jb + kg * 8;
    const unsigned short* Hpb = HpT + (size_t)(b * H) * D * N;

    #pragma unroll 2
    for (int s = 0; s < NSTEP; ++s) {
        // ---- loads for this step (no barriers; compiler pipelines) ----
        int4 a0 = Ar[s * 8];
        int4 a1 = Ar[s * 8 + 1];
        float4 h2lo[H], h2hi[H];
        #pragma unroll
        for (int h = 0; h < H; ++h) {
            const float4* hp = (const float4*)(H2b + (size_t)h * N) + s * 8;
            h2lo[h] = hp[0];
            h2hi[h] = hp[1];
        }

        // ---- softmax for 8 pairs, all 4 heads, in registers ----
        bf16x8 af[H];
        #pragma unroll
        for (int e = 0; e < 8; ++e) {
            int aij = (e < 4) ? ((const int*)&a0)[e] : ((const int*)&a1)[e - 4];
            float sc0, sc1, sc2, sc3;
            {
                float v0 = h1v[0] + ((e < 4) ? ((const float*)&h2lo[0])[e] : ((const float*)&h2hi[0])[e - 4]);
                float v1 = h1v[1] + ((e < 4) ? ((const float*)&h2lo[1])[e] : ((const float*)&h2hi[1])[e - 4]);
                float v2 = h1v[2] + ((e < 4) ? ((const float*)&h2lo[2])[e] : ((const float*)&h2hi[2])[e - 4]);
                float v3 = h1v[3] + ((e < 4) ? ((const float*)&h2lo[3])[e] : ((const float*)&h2hi[3])[e - 4]);
                sc0 = fmaxf(v0, 0.2f * v0); // leaky-relu (log2-scaled domain)
                sc1 = fmaxf(v1, 0.2f * v1);
                sc2 = fmaxf(v2, 0.2f * v2);
                sc3 = fmaxf(v3, 0.2f * v3);
            }
            float m = fmaxf(fmaxf(sc0, sc1), fmaxf(sc2, sc3));
            float e0 = exp2f(sc0 - m);
            float e1 = exp2f(sc1 - m);
            float e2 = exp2f(sc2 - m);
            float e3 = exp2f(sc3 - m);
            float zi = __builtin_amdgcn_rcpf(e0 + e1 + e2 + e3);
            bool on = aij > 0;
            af[0][e] = (__bf16)(on ? e0 * zi : 0.25f);
            af[1][e] = (__bf16)(on ? e1 * zi : 0.25f);
            af[2][e] = (__bf16)(on ? e2 * zi : 0.25f);
            af[3][e] = (__bf16)(on ? e3 * zi : 0.25f);
        }

        // ---- MFMA: 4 heads x 4 d-tiles ----
        #pragma unroll
        for (int h = 0; h < H; ++h) {
            #pragma unroll
            for (int nt = 0; nt < 4; ++nt) {
                const us8* bp = (const us8*)(Hpb + ((size_t)h * D + row + 16 * nt) * N + jb + kg * 8 + s * 32);
                bf16x8 bfr = __builtin_bit_cast(bf16x8, bp[0]);
                acc[h][nt] = __builtin_amdgcn_mfma_f32_16x16x32_bf16(af[h], bfr, acc[h][nt], 0, 0, 0);
            }
        }
    }

    // ---- epilogue: C/D col = l&15, row = (l>>4)*4 + r; store bf16 partial ----
    #pragma unroll
    for (int h = 0; h < H; ++h) {
        #pragma unroll
        for (int nt = 0; nt < 4; ++nt) {
            #pragma unroll
            for (int r = 0; r < 4; ++r) {
                int i = kg * 4 + r;
                part[(size_t)js * PART + ((size_t)(b * H + h) * N + i0 + i) * D + row + 16 * nt] =
                    f2bf(acc[h][nt][r]);
            }
        }
    }
}

// ---------------- Kernel 3: out = (sum of 4 bf16 partials) @ W_out^T + b_out ----------------
constexpr int R3 = 16; // rows per block
constexpr int ET = 32; // e' tile

__global__ __launch_bounds__(256) void k_out(const unsigned short* __restrict__ part,
                                             const float* __restrict__ Wo,
                                             const float* __restrict__ bo,
                                             float* __restrict__ out) {
    int row0 = blockIdx.x * R3;
    int t = threadIdx.x;

    __shared__ float Rs[R3][E];       // 16 KB
    __shared__ float WT[ET][E + 1];   // 32.1 KB

    // stage rows: sum the 4 bf16 partials -> f32
    #pragma unroll
    for (int k = 0; k < 2; ++k) { // R3*E/8 = 512 us8 chunks / 256 threads
        int v = t + 256 * k;
        float s8[8] = {0.f, 0.f, 0.f, 0.f, 0.f, 0.f, 0.f, 0.f};
        #pragma unroll
        for (int js = 0; js < JSPL; ++js) {
            us8 raw = *((const us8*)(part + (size_t)js * PART) + (size_t)row0 * E / 8 + v);
            #pragma unroll
            for (int e = 0; e < 8; ++e) s8[e] += bf2f(raw[e]);
        }
        float* dst = &((float*)Rs)[(size_t)v * 8];
        *(float4*)(dst + 0) = make_float4(s8[0], s8[1], s8[2], s8[3]);
        *(float4*)(dst + 4) = make_float4(s8[4], s8[5], s8[6], s8[7]);
    }

    float acc[R3];
    float bias = bo[t];
    #pragma unroll
    for (int i = 0; i < R3; ++i) acc[i] = bias;

    for (int et = 0; et < E / ET; ++et) { // 8 tiles
        __syncthreads();
        int c_l = t & 31;
        int rbase = t >> 5;
        #pragma unroll 8
        for (int k = 0; k < 32; ++k) {
            int r = rbase + 8 * k;
            WT[c_l][r] = Wo[(size_t)r * E + et * ET + c_l];
        }
        __syncthreads();

        #pragma unroll 4
        for (int cg = 0; cg < ET / 4; ++cg) {
            float w0 = WT[cg * 4 + 0][t];
            float w1 = WT[cg * 4 + 1][t];
            float w2 = WT[cg * 4 + 2][t];
            float w3 = WT[cg * 4 + 3][t];
            #pragma unroll
            for (int i = 0; i < R3; ++i) {
                float4 rv = *(const float4*)&Rs[i][et * ET + cg * 4];
                acc[i] += rv.x * w0 + rv.y * w1 + rv.z * w2 + rv.w * w3;
            }
        }
    }

    #pragma unroll
    for (int i = 0; i < R3; ++i) {
        out[(size_t)(row0 + i) * E + t] = acc[i];
    }
}

extern "C" void kernel_launch(void* const* d_in, const int* in_sizes, int n_in,
                              void* d_out, int out_size, void* d_ws, size_t ws_size,
                              hipStream_t stream) {
    const float* X  = (const float*)d_in[0];
    const int*   A  = (const int*)d_in[1];
    const float* W  = (const float*)d_in[2];
    const float* a  = (const float*)d_in[3];
    const float* Wo = (const float*)d_in[4];
    const float* bo = (const float*)d_in[5];
    float* out = (float*)d_out;

    // workspace layout (u16 units): 4 bf16 partials, HpT bf16, then f32 H1/H2
    unsigned short* wsu  = (unsigned short*)d_ws;
    unsigned short* part = wsu;                        // 4 * PART u16 = 16.8 MB
    unsigned short* HpT  = wsu + (size_t)4 * PART;     // PART u16 = 4.2 MB
    float* H1 = (float*)(wsu + (size_t)5 * PART);      // 32768 floats
    float* H2 = H1 + B * H * N;                        // 32768 floats

    k_proj<<<dim3(B * N / NT), dim3(256), 0, stream>>>(X, W, a, HpT, H1, H2);
    k_agg<<<dim3(B * (N / 16) * JSPL), dim3(64), 0, stream>>>(A, H1, H2, HpT, part);
    k_out<<<dim3(B * N / R3), dim3(256), 0, stream>>>(part, Wo, bo, out);
}